// Round 1
// baseline (388.599 us; speedup 1.0000x reference)
//
#include <hip/hip_runtime.h>

// HiPPO-LegT projection: c_t = A c_{t-1} + B f_t, c_0-before = 0, emit all c_t.
// Since the initial state is zero, the exact closed form is a causal
// convolution:  out[t][s][n] = sum_{j<=t} K_{t-j}[n] * f[s][j],  K_i = A^i B.
// => ONE causal GEMM (M=2048 seq, N=512*64 (tau,n) cols, K<=512), no serial
// chunk chain (the old 8 stream-serialized chunk launches were the bottleneck).
//
// Weight is block-Toeplitz: W[(tau,n)][j] = K_{tau-j}[n] (0 if j>tau).
// Compact table L[n][y] = K_{511-y}[n] for y<=511, 0 for y>511; row tau,
// element j lives at y = 511 - tau + j (zeros implement the causal mask).
// Stored as 8 pre-shifted copies Lc[c][n][z] = L[n][z+c] (1 MB, L2-resident)
// so staging reads are always 16B-aligned uint4: pick c = o & 7, read at o-c.
//
// Precompute: power_kernel (512 blocks; block i computes A^i by binary exp in
// f32 LDS via mul64, then K_i = A^i B -> Kg), fill_kernel (Kg -> 8-shift Lc,
// f16), fh_kernel (f -> f16 once, halves staging traffic).
// Main: causal_gemm, grid 256(N) x 16(M), 128x128 tile, per-block K-extent
// KH = ceil((2bn+2)/64); heavy blocks dispatched first (bn = 255 - x).

typedef _Float16 half8  __attribute__((ext_vector_type(8)));
typedef _Float16 half4t __attribute__((ext_vector_type(4)));
typedef float    f32x4  __attribute__((ext_vector_type(4)));

#define SEQN 2048
#define LT   512

// ---------------------------------------------------------------------------
// 64x64 f32 matmul in LDS: C = X*Y given XT (X transposed) and Y.
// 512 threads, each computes a 4x2 output block. Optionally writes result
// transposed (outT) and/or normal (outN), in place is safe (reads finish
// before the internal barrier).
__device__ __forceinline__ void mul64(const float* XT, const float* Y,
                                      float* outT, float* outN, int t) {
  const int r = (t >> 5) * 4;
  const int c = (t & 31) * 2;
  float a00 = 0.f, a01 = 0.f, a10 = 0.f, a11 = 0.f;
  float a20 = 0.f, a21 = 0.f, a30 = 0.f, a31 = 0.f;
#pragma unroll 4
  for (int l = 0; l < 64; ++l) {
    const float4 x = *(const float4*)(XT + l * 64 + r);
    const float2 y = *(const float2*)(Y + l * 64 + c);
    a00 += x.x * y.x; a01 += x.x * y.y;
    a10 += x.y * y.x; a11 += x.y * y.y;
    a20 += x.z * y.x; a21 += x.z * y.y;
    a30 += x.w * y.x; a31 += x.w * y.y;
  }
  __syncthreads();
  if (outT) {
    outT[(c + 0) * 64 + r + 0] = a00; outT[(c + 1) * 64 + r + 0] = a01;
    outT[(c + 0) * 64 + r + 1] = a10; outT[(c + 1) * 64 + r + 1] = a11;
    outT[(c + 0) * 64 + r + 2] = a20; outT[(c + 1) * 64 + r + 2] = a21;
    outT[(c + 0) * 64 + r + 3] = a30; outT[(c + 1) * 64 + r + 3] = a31;
  }
  if (outN) {
    outN[(r + 0) * 64 + c + 0] = a00; outN[(r + 0) * 64 + c + 1] = a01;
    outN[(r + 1) * 64 + c + 0] = a10; outN[(r + 1) * 64 + c + 1] = a11;
    outN[(r + 2) * 64 + c + 0] = a20; outN[(r + 2) * 64 + c + 1] = a21;
    outN[(r + 3) * 64 + c + 0] = a30; outN[(r + 3) * 64 + c + 1] = a31;
  }
  __syncthreads();
}

// Block i (0..511): K_i = A^i B in f32. Binary exponentiation in f32 LDS.
__global__ __launch_bounds__(512) void power_kernel(
    const float* __restrict__ A, const float* __restrict__ B,
    float* __restrict__ Kg) {
  __shared__ float S[4096];    // current square-chain power (normal)
  __shared__ float STr[4096];  // same, transposed
  __shared__ float RT[4096];   // accumulated result, transposed
  const int t = threadIdx.x;
  const int d = blockIdx.x;
  if (d == 0) {  // K_0 = B
    if (t < 64) Kg[t] = B[t];
    return;
  }

  for (int i = t; i < 4096; i += 512) {
    const float v = A[i];
    S[i] = v;
    STr[(i & 63) * 64 + (i >> 6)] = v;
  }
  __syncthreads();

  bool rvalid = false;
  int e = d;
  while (e) {
    if (e & 1) {
      if (!rvalid) {
        for (int i = t; i < 4096; i += 512) RT[i] = STr[i];  // R = S
        rvalid = true;
        __syncthreads();
      } else {
        mul64(RT, S, RT, nullptr, t);  // R = R*S (store transposed)
      }
    }
    e >>= 1;
    if (e) mul64(STr, S, STr, S, t);   // S = S*S (both forms)
  }
  // RT[m*64+n] = (A^d)[n][m];  K_d[n] = sum_m A^d[n][m] B[m]
  if (t < 64) {
    float s = 0.f;
    for (int m = 0; m < 64; ++m) s += RT[m * 64 + t] * B[m];
    Kg[d * 64 + t] = s;
  }
}

// Fill the 8-shift compact table: Lc[c][n][z] = (z+c<=511)? K_{511-z-c}[n] : 0
// Grid: 512 blocks = (c,n) pairs; 256 threads x 4 halves = 1024 z each.
__global__ __launch_bounds__(256) void fill_kernel(
    const float* __restrict__ Kg, _Float16* __restrict__ Lc) {
  const int c = blockIdx.x >> 6;
  const int n = blockIdx.x & 63;
  const int z0 = threadIdx.x * 4;
  half4t v;
#pragma unroll
  for (int zz = 0; zz < 4; ++zz) {
    const int i = 511 - (z0 + zz) - c;
    v[zz] = (i >= 0) ? (_Float16)Kg[i * 64 + n] : (_Float16)0.f;
  }
  *(half4t*)(Lc + (size_t)blockIdx.x * 1024 + z0) = v;
}

// One-shot f32 -> f16 cast of the inputs (2048 x 512).
__global__ __launch_bounds__(256) void fh_kernel(const float* __restrict__ f,
                                                 _Float16* __restrict__ fh) {
  const size_t g = (size_t)blockIdx.x * 256 + threadIdx.x;
  const float4* s = (const float4*)(f + g * 8);
  const float4 a = s[0], b = s[1];
  half8 v;
  v[0] = (_Float16)a.x; v[1] = (_Float16)a.y;
  v[2] = (_Float16)a.z; v[3] = (_Float16)a.w;
  v[4] = (_Float16)b.x; v[5] = (_Float16)b.y;
  v[6] = (_Float16)b.z; v[7] = (_Float16)b.w;
  *(half8*)(fh + g * 8) = v;
}

// Causal GEMM: out-tile 128(seq) x 128(col=(tau,n)), K = 64*KH (causal).
// 4 waves in 2x2; each wave: 64x64 via 4x4 grid of 16x16x32 f16 MFMA.
__global__ __launch_bounds__(256) void causal_gemm(
    const _Float16* __restrict__ fh, const _Float16* __restrict__ Lc,
    float* __restrict__ out) {
  __shared__ _Float16 Xs[128 * 72];  // [seq-local][k]  (pad 64->72)
  __shared__ _Float16 Ws[128 * 72];  // [col-local][k]

  const int tid = threadIdx.x;
  const int bn = 255 - (int)blockIdx.x;  // heavy (large-K) blocks first
  const int bm = blockIdx.y;             // 0..15 M-tiles
  const int lane = tid & 63, wid = tid >> 6;
  const int wm = wid >> 1, wn = wid & 1;
  const int l15 = lane & 15, quad = lane >> 4;
  const int KH = (2 * bn + 65) >> 6;  // ceil((2bn+2)/64), 1..8

  // staging role: thread (r,h) covers halves [h*32, h*32+32) of row r
  const int r = tid >> 1, h = tid & 1;
  const int tau = 2 * bn + (r >> 6);  // W-row tau for col-local r
  const int n = r & 63;               // W-row n
  const _Float16* xsrc = fh + (size_t)(bm * 128 + r) * LT + h * 32;

  f32x4 acc[4][4];
  const f32x4 z4 = {0.f, 0.f, 0.f, 0.f};
#pragma unroll
  for (int i = 0; i < 4; ++i)
#pragma unroll
    for (int j = 0; j < 4; ++j) acc[i][j] = z4;

  for (int kh = 0; kh < KH; ++kh) {
    if (kh) __syncthreads();  // protect LDS before overwrite
    // ---- stage X half (64 k of f16 inputs) ----
    {
      const uint4* s = (const uint4*)(xsrc + kh * 64);
#pragma unroll
      for (int i = 0; i < 4; ++i)
        *(uint4*)&Xs[r * 72 + h * 32 + i * 8] = s[i];
    }
    // ---- stage W half from the shifted compact table ----
    {
      const int o = 511 - tau + kh * 64;  // y-offset of j0 in L
      const int c = o & 7;                // shift copy -> aligned reads
      const uint4* s = (const uint4*)(Lc + (size_t)c * 65536 + n * 1024 +
                                      (o - c) + h * 32);
#pragma unroll
      for (int i = 0; i < 4; ++i)
        *(uint4*)&Ws[r * 72 + h * 32 + i * 8] = s[i];
    }
    __syncthreads();

#pragma unroll
    for (int kk = 0; kk < 2; ++kk) {
      half8 av[4], bv[4];
#pragma unroll
      for (int fm = 0; fm < 4; ++fm)
        av[fm] = *(const half8*)&Xs[(wm * 64 + fm * 16 + l15) * 72 + kk * 32 +
                                    quad * 8];
#pragma unroll
      for (int fn = 0; fn < 4; ++fn)
        bv[fn] = *(const half8*)&Ws[(wn * 64 + fn * 16 + l15) * 72 + kk * 32 +
                                    quad * 8];
#pragma unroll
      for (int fm = 0; fm < 4; ++fm)
#pragma unroll
        for (int fn = 0; fn < 4; ++fn)
          acc[fm][fn] = __builtin_amdgcn_mfma_f32_16x16x32_f16(
              av[fm], bv[fn], acc[fm][fn], 0, 0, 0);
    }
  }

  // ---- epilogue: D row = quad*4+reg (seq), col = lane&15 (n) ----
  const int taug = bn * 2 + wn;  // wave's tau slab
#pragma unroll
  for (int fm = 0; fm < 4; ++fm) {
#pragma unroll
    for (int rr = 0; rr < 4; ++rr) {
      const size_t row =
          (size_t)taug * SEQN + (bm * 128 + wm * 64 + fm * 16 + quad * 4 + rr);
      float* o = out + row * 64 + l15;
#pragma unroll
      for (int fn = 0; fn < 4; ++fn) o[fn * 16] = acc[fm][fn][rr];
    }
  }
}

extern "C" void kernel_launch(void* const* d_in, const int* in_sizes, int n_in,
                              void* d_out, int out_size, void* d_ws,
                              size_t ws_size, hipStream_t stream) {
  const float* f = (const float*)d_in[0];  // (16,128,512) -> (2048, 512)
  const float* A = (const float*)d_in[1];  // (64,64)
  const float* B = (const float*)d_in[2];  // (64,)
  float* out = (float*)d_out;              // (512, 2048, 64)

  _Float16* Lc = (_Float16*)d_ws;                           // 8*64*1024*2 = 1 MB
  float* Kg = (float*)((char*)d_ws + (1 << 20));            // 512*64*4 = 128 KB
  _Float16* fh =
      (_Float16*)((char*)d_ws + (1 << 20) + (128 << 10));   // 2048*512*2 = 2 MB

  power_kernel<<<512, 512, 0, stream>>>(A, B, Kg);
  fill_kernel<<<512, 256, 0, stream>>>(Kg, Lc);
  fh_kernel<<<512, 256, 0, stream>>>(f, fh);
  causal_gemm<<<dim3(256, 16), 256, 0, stream>>>(fh, Lc, out);
}

// Round 2
// 310.697 us; speedup vs baseline: 1.2507x; 1.2507x over previous
//
#include <hip/hip_runtime.h>

// HiPPO-LegT projection: c_t = A c_{t-1} + B f_t, zero init, emit all c_t.
// Closed form (zero init): causal convolution out[t][s][n] = sum_{j<=t}
// K_{t-j}[n] f[s][j], K_i = A^i B  =>  ONE causal GEMM (M=2048, N=512*64,
// K<=512 triangular).
//
// Weight is block-Toeplitz. Compact table L[n][y] = K_{511-y}[n] (y<=511),
// 0 for y>511; row tau, element j at y = 511-tau+j (zeros = causal mask).
// 8 pre-shifted copies Lc[c][n][z] = L[n][z+c] so every 64-half staging
// window is 16B-aligned: pick c = o&7, read at o-c.
//
// Launch 1 squares_fh: block 0 computes SqT[k] = (A^{2^k})^T (8 serial mul64);
//   blocks 1..256 cast f -> f16 (fh) in parallel.
// Launch 2 kvec_fill: 64 blocks x 8 groups; group computes K_i by chaining
//   mat-vecs against SqT (bits of i), scatters the 8 Lc shift-copies, zeros
//   the y>511 tail.
// Launch 3 causal_gemm: 128x128 tile, K = 64*KH, KH = ceil((2bn+2)/64).
//   Staging via global_load_lds dwordx4 (linear LDS dest); XOR chunk-swizzle
//   j^(row&7) applied on the per-lane GLOBAL source and on the ds_read addr
//   (both-sides involution) -> conflict-free b128 reads, no reg roundtrip.

typedef _Float16 half8  __attribute__((ext_vector_type(8)));
typedef float    f32x4  __attribute__((ext_vector_type(4)));

#define SEQN 2048
#define LT   512

typedef const __attribute__((address_space(1))) unsigned int kGU32;
typedef __attribute__((address_space(3))) unsigned int kLU32;

// async global->LDS, 16B per lane; l must be wave-uniform (dest = l + lane*16)
__device__ __forceinline__ void cp16(const void* g, void* l) {
  __builtin_amdgcn_global_load_lds((kGU32*)g, (kLU32*)l, 16, 0, 0);
}

// ---------------------------------------------------------------------------
// 64x64 f32 matmul in LDS: C = X*Y given XT (X transposed) and Y.
// 512 threads, 4x2 output per thread. Writes outT (=C^T) / outN; in-place ok.
__device__ __forceinline__ void mul64(const float* XT, const float* Y,
                                      float* outT, float* outN, int t) {
  const int r = (t >> 5) * 4;
  const int c = (t & 31) * 2;
  float a00 = 0.f, a01 = 0.f, a10 = 0.f, a11 = 0.f;
  float a20 = 0.f, a21 = 0.f, a30 = 0.f, a31 = 0.f;
#pragma unroll 4
  for (int l = 0; l < 64; ++l) {
    const float4 x = *(const float4*)(XT + l * 64 + r);
    const float2 y = *(const float2*)(Y + l * 64 + c);
    a00 += x.x * y.x; a01 += x.x * y.y;
    a10 += x.y * y.x; a11 += x.y * y.y;
    a20 += x.z * y.x; a21 += x.z * y.y;
    a30 += x.w * y.x; a31 += x.w * y.y;
  }
  __syncthreads();
  if (outT) {
    outT[(c + 0) * 64 + r + 0] = a00; outT[(c + 1) * 64 + r + 0] = a01;
    outT[(c + 0) * 64 + r + 1] = a10; outT[(c + 1) * 64 + r + 1] = a11;
    outT[(c + 0) * 64 + r + 2] = a20; outT[(c + 1) * 64 + r + 2] = a21;
    outT[(c + 0) * 64 + r + 3] = a30; outT[(c + 1) * 64 + r + 3] = a31;
  }
  if (outN) {
    outN[(r + 0) * 64 + c + 0] = a00; outN[(r + 0) * 64 + c + 1] = a01;
    outN[(r + 1) * 64 + c + 0] = a10; outN[(r + 1) * 64 + c + 1] = a11;
    outN[(r + 2) * 64 + c + 0] = a20; outN[(r + 2) * 64 + c + 1] = a21;
    outN[(r + 3) * 64 + c + 0] = a30; outN[(r + 3) * 64 + c + 1] = a31;
  }
  __syncthreads();
}

// Block 0: SqT[k][m*64+n] = (A^{2^k})[n][m], k=0..8 (serial squaring chain).
// Blocks 1..256: f32 -> f16 cast of inputs (independent, hides under block 0).
__global__ __launch_bounds__(512) void squares_fh(
    const float* __restrict__ A, const float* __restrict__ f,
    float* __restrict__ SqT, _Float16* __restrict__ fh) {
  __shared__ float S[4096];    // current power, normal
  __shared__ float STr[4096];  // current power, transposed
  const int t = threadIdx.x;
  if (blockIdx.x == 0) {
    for (int i = t; i < 4096; i += 512) {
      const float v = A[i];
      S[i] = v;
      STr[(i & 63) * 64 + (i >> 6)] = v;
    }
    __syncthreads();
    for (int i = t; i < 4096; i += 512) SqT[i] = STr[i];  // k=0
    for (int k = 1; k < 9; ++k) {
      mul64(STr, S, STr, S, t);  // S = S*S (both forms)
      for (int i = t; i < 4096; i += 512) SqT[k * 4096 + i] = STr[i];
    }
  } else {
    const size_t g = (size_t)(blockIdx.x - 1) * 512 + t;
    const float4* s = (const float4*)(f + g * 8);
    const float4 a = s[0], b = s[1];
    half8 v;
    v[0] = (_Float16)a.x; v[1] = (_Float16)a.y;
    v[2] = (_Float16)a.z; v[3] = (_Float16)a.w;
    v[4] = (_Float16)b.x; v[5] = (_Float16)b.y;
    v[6] = (_Float16)b.z; v[7] = (_Float16)b.w;
    *(half8*)(fh + g * 8) = v;
  }
}

// 64 blocks x 512 threads: group g (wave) computes K_i, i = 8*blk + g, by
// chaining mat-vecs K = A^{2^k} K over set bits of i (commuting powers).
// Then scatter f16 into the 8 shift copies; zero the z+c>511 tail.
__global__ __launch_bounds__(512) void kvec_fill(
    const float* __restrict__ SqT, const float* __restrict__ B,
    _Float16* __restrict__ Lc) {
  __shared__ float Kb[8][64];
  const int t = threadIdx.x;
  const int b = blockIdx.x;

  // zero tail z in [512,1024): one 16B chunk per thread (32768 total)
  {
    const int ch = b * 512 + t;
    const int c = ch >> 12, n = (ch >> 6) & 63, zc = ch & 63;
    const uint4 zz = {0u, 0u, 0u, 0u};
    *(uint4*)(Lc + (size_t)c * 65536 + n * 1024 + 512 + zc * 8) = zz;
  }
  // zero straggler tail z in [512-c, 512), c>=1 (1792 scalar f16)
  if (b == 0) {
    for (int e = t; e < 1792; e += 512) {
      int e2 = e, c = 1;
      while (e2 >= 64 * c) { e2 -= 64 * c; ++c; }
      const int n = e2 & 63, dz = e2 >> 6;
      Lc[(size_t)c * 65536 + n * 1024 + (512 - c + dz)] = (_Float16)0.f;
    }
  }

  const int g = t >> 6, n = t & 63;
  const int i = b * 8 + g;
  float kreg = B[n];
  for (int k = 0; k < 9; ++k) {
    Kb[g][n] = kreg;
    __syncthreads();
    if ((i >> k) & 1) {  // uniform per wave
      const float* Sk = SqT + k * 4096 + n;  // column n, SqT[m*64+n]=A[n][m]
      float s = 0.f;
#pragma unroll 16
      for (int m = 0; m < 64; ++m) s += Sk[m * 64] * Kb[g][m];
      kreg = s;
    }
    __syncthreads();
  }
  // K_i -> 8 shift copies: Lc[c][n][511-i-c]
#pragma unroll
  for (int c = 0; c < 8; ++c) {
    const int z = 511 - i - c;
    if (z >= 0) Lc[(size_t)c * 65536 + n * 1024 + z] = (_Float16)kreg;
  }
}

// Causal GEMM: out-tile 128(seq) x 128(col=(tau,n)), K = 64*KH.
// 4 waves 2x2; each wave 64x64 via 4x4 of 16x16x32 f16 MFMA.
// LDS rows 64 halves (128B, linear); content chunk-swizzled j^(row&7) via
// per-lane global source; ds_read applies the same XOR -> conflict-free.
__global__ __launch_bounds__(256) void causal_gemm(
    const _Float16* __restrict__ fh, const _Float16* __restrict__ Lc,
    float* __restrict__ out) {
  __shared__ _Float16 Xs[128 * 64];
  __shared__ _Float16 Ws[128 * 64];

  const int tid = threadIdx.x;
  const int bn = 255 - (int)blockIdx.x;  // heavy (large-K) blocks first
  const int bm = blockIdx.y;
  const int lane = tid & 63, wid = tid >> 6;
  const int wm = wid >> 1, wn = wid & 1;
  const int l15 = lane & 15, quad = lane >> 4;
  const int KH = (2 * bn + 65) >> 6;  // ceil((2bn+2)/64), 1..8

  // staging lane geometry: lane -> (srow = lane>>3 within 8-row slab,
  // dest chunk j = lane&7); fetch global chunk jp = j ^ (row&7)
  const int srow = lane >> 3;
  const int jp = (lane & 7) ^ srow;
  const _Float16* xbase =
      fh + (size_t)(bm * 128 + wid * 32 + srow) * LT + jp * 8;

  f32x4 acc[4][4];
  const f32x4 z4 = {0.f, 0.f, 0.f, 0.f};
#pragma unroll
  for (int i = 0; i < 4; ++i)
#pragma unroll
    for (int j = 0; j < 4; ++j) acc[i][j] = z4;

  for (int kh = 0; kh < KH; ++kh) {
    if (kh) __syncthreads();  // MFMA reads of prev step done before overwrite
#pragma unroll
    for (int q = 0; q < 4; ++q) {
      const int rl = wid * 32 + q * 8 + srow;  // lds row 0..127 (rl&7 == srow)
      // X slab
      cp16(xbase + (size_t)q * 8 * LT + kh * 64, Xs + (wid * 32 + q * 8) * 64);
      // W slab from shifted compact table
      const int tau = 2 * bn + (rl >> 6);
      const int n = rl & 63;
      const int o = 511 - tau + kh * 64;  // y-offset of j0 in L
      const int c = o & 7;                // shift copy -> 16B-aligned window
      cp16(Lc + (size_t)c * 65536 + n * 1024 + (o - c) + jp * 8,
           Ws + (wid * 32 + q * 8) * 64);
    }
    __syncthreads();  // drains vmcnt(0): gload_lds data visible to all waves

#pragma unroll
    for (int kk = 0; kk < 2; ++kk) {
      half8 av[4], bv[4];
#pragma unroll
      for (int fm = 0; fm < 4; ++fm) {
        const int r = wm * 64 + fm * 16 + l15;
        av[fm] =
            *(const half8*)&Xs[r * 64 + (((kk * 4 + quad) ^ (l15 & 7)) << 3)];
      }
#pragma unroll
      for (int fn = 0; fn < 4; ++fn) {
        const int r = wn * 64 + fn * 16 + l15;
        bv[fn] =
            *(const half8*)&Ws[r * 64 + (((kk * 4 + quad) ^ (l15 & 7)) << 3)];
      }
#pragma unroll
      for (int fm = 0; fm < 4; ++fm)
#pragma unroll
        for (int fn = 0; fn < 4; ++fn)
          acc[fm][fn] = __builtin_amdgcn_mfma_f32_16x16x32_f16(
              av[fm], bv[fn], acc[fm][fn], 0, 0, 0);
    }
  }

  // epilogue: D row = quad*4+reg (seq), col = lane&15 (n)
  const int taug = bn * 2 + wn;
#pragma unroll
  for (int fm = 0; fm < 4; ++fm) {
#pragma unroll
    for (int rr = 0; rr < 4; ++rr) {
      const size_t row =
          (size_t)taug * SEQN + (bm * 128 + wm * 64 + fm * 16 + quad * 4 + rr);
      float* o = out + row * 64 + l15;
#pragma unroll
      for (int fn = 0; fn < 4; ++fn) o[fn * 16] = acc[fm][fn][rr];
    }
  }
}

extern "C" void kernel_launch(void* const* d_in, const int* in_sizes, int n_in,
                              void* d_out, int out_size, void* d_ws,
                              size_t ws_size, hipStream_t stream) {
  const float* f = (const float*)d_in[0];  // (16,128,512) -> (2048, 512)
  const float* A = (const float*)d_in[1];  // (64,64)
  const float* B = (const float*)d_in[2];  // (64,)
  float* out = (float*)d_out;              // (512, 2048, 64)

  _Float16* Lc = (_Float16*)d_ws;                        // 8*64*1024*2 = 1 MB
  float* SqT = (float*)((char*)d_ws + (1 << 20));        // 9*4096*4 = 144 KB
  _Float16* fh =
      (_Float16*)((char*)d_ws + (1 << 20) + (192 << 10));  // 2048*512*2 = 2 MB

  squares_fh<<<257, 512, 0, stream>>>(A, f, SqT, fh);
  kvec_fill<<<64, 512, 0, stream>>>(SqT, B, Lc);
  causal_gemm<<<dim3(256, 16), 256, 0, stream>>>(fh, Lc, out);
}